// Round 11
// baseline (222.408 us; speedup 1.0000x reference)
//
#include <hip/hip_runtime.h>
#include <hip/hip_bf16.h>

// Problem constants: features [B=32, D=1024, M=512] fp32.
#define B_ 32
#define D_ 1024
#define M_ 512
#define OUTROW 524800  // D*(D+1)/2
#define ALPHA_ 0.4f
#define EPS_ 1e-5f

typedef __bf16 bf16x8 __attribute__((ext_vector_type(8)));
typedef __bf16 bf16x4 __attribute__((ext_vector_type(4)));
typedef float f32x4 __attribute__((ext_vector_type(4)));

// ---------------------------------------------------------------------------
// Kernel B (now the ONLY heavy kernel): upper-triangular-tile Gram GEMM with
// PREP FUSED IN. Reads fp32 feat directly; staging path is reg-staged
// (global fp32 -> cvt bf16 -> ds_write) which (a) deletes the prep kernel +
// featbf array entirely and (b) computes diag in-staging from the fp32
// values (each (row,octet) loaded exactly once by exactly one thread;
// 4-lane shfl reduce -> LDS -> epilogue).
// LDS layout/read-side swizzle BIT-IDENTICAL to the proven R3 kernel:
// chunk slot (t&3) holds global octet (t&3)^((row>>1)&3).
// Pipeline: 3 register stage-slots (depth-2 latency cover), 2 LDS buffers,
// counted s_waitcnt vmcnt(16/8/0), one lgkmcnt(0)+s_barrier per k-step,
// setprio around the MFMA cluster. Epilogue (dcov->pow->bf16 pbuf +
// rowsum/totals atomics) unchanged from R9/R10.
// ---------------------------------------------------------------------------
__global__ __launch_bounds__(256, 2) void gram_kernel(
    const float* __restrict__ feat,
    float* __restrict__ out, __bf16* __restrict__ pbuf,
    float* __restrict__ rowsum, float* __restrict__ totals, int useP)
{
    __shared__ __bf16 As[2][512 * 8];
    __shared__ __bf16 Bs[2][512 * 8];
    __shared__ float dshA[128];
    __shared__ float dshB[128];

    const int t = threadIdx.x;
    const int w = t >> 6, l = t & 63;
    const int quad = l >> 4, l15 = l & 15;

    // XCD-aware decode: each XCD owns batches {xcd, xcd+8, xcd+16, xcd+24}.
    const int L = blockIdx.x;
    const int xcd = L & 7;
    const int slot = L >> 3;                 // 0..143
    const int b = xcd + 8 * (slot / 36);
    int u = slot % 36, ti = 0;
    while (u >= 8 - ti) { u -= 8 - ti; ti++; }
    const int tj = ti + u;
    const bool diagTile = (ti == tj);

    const float* Af = feat + (size_t)b * (D_ * M_) + (size_t)ti * 128 * M_;
    const float* Bf = feat + (size_t)b * (D_ * M_) + (size_t)tj * 128 * M_;

    const int wm = w >> 1, wn = w & 1;

    // Staging geometry (fixed per thread): rows r0 (it=0) / r1 (it=1),
    // LDS chunk slot sl = t&3, global octet cg = sl ^ swz(row).
    // ((r1>>1)&3) == ((r0>>1)&3) since r1 = r0+64, so one cg serves both.
    const int r0 = t >> 2;                   // 0..63
    const int r1 = 64 + r0;                  // 64..127
    const int sl = t & 3;
    const int cg = sl ^ ((r0 >> 1) & 3);
    const float* gA0 = Af + (size_t)r0 * M_ + cg * 8;
    const float* gA1 = Af + (size_t)r1 * M_ + cg * 8;
    const float* gB0 = Bf + (size_t)r0 * M_ + cg * 8;
    const float* gB1 = Bf + (size_t)r1 * M_ + cg * 8;

    f32x4 acc[4][4] = {};
    float4 rg[3][8];                         // 3 in-flight stage slots
    float dA0 = 0.f, dA1 = 0.f, dB0 = 0.f, dB1 = 0.f;

#define ISSUE(S, KS) {                                   \
    const int ko = (KS) * 32;                            \
    rg[S][0] = *(const float4*)(gA0 + ko);               \
    rg[S][1] = *(const float4*)(gA0 + ko + 4);           \
    rg[S][2] = *(const float4*)(gA1 + ko);               \
    rg[S][3] = *(const float4*)(gA1 + ko + 4);           \
    rg[S][4] = *(const float4*)(gB0 + ko);               \
    rg[S][5] = *(const float4*)(gB0 + ko + 4);           \
    rg[S][6] = *(const float4*)(gB1 + ko);               \
    rg[S][7] = *(const float4*)(gB1 + ko + 4); }

#define CVT8(H, VA, VB)                                                        \
    H[0]=(__bf16)VA.x; H[1]=(__bf16)VA.y; H[2]=(__bf16)VA.z; H[3]=(__bf16)VA.w;\
    H[4]=(__bf16)VB.x; H[5]=(__bf16)VB.y; H[6]=(__bf16)VB.z; H[7]=(__bf16)VB.w;

#define SQ8(VA, VB) (VA.x*VA.x + VA.y*VA.y + VA.z*VA.z + VA.w*VA.w +           \
                     VB.x*VB.x + VB.y*VB.y + VB.z*VB.z + VB.w*VB.w)

    // cvt + ds_write stage S into LDS buffer SB; accumulate fp32 diag partials
#define CVW(S, SB) {                                     \
    float4 va, vb; bf16x8 h;                             \
    va = rg[S][0]; vb = rg[S][1];                        \
    CVT8(h, va, vb)                                      \
    *(bf16x8*)(&As[SB][(r0 * 4 + sl) * 8]) = h;          \
    dA0 += SQ8(va, vb);                                  \
    va = rg[S][2]; vb = rg[S][3];                        \
    CVT8(h, va, vb)                                      \
    *(bf16x8*)(&As[SB][(r1 * 4 + sl) * 8]) = h;          \
    dA1 += SQ8(va, vb);                                  \
    va = rg[S][4]; vb = rg[S][5];                        \
    CVT8(h, va, vb)                                      \
    *(bf16x8*)(&Bs[SB][(r0 * 4 + sl) * 8]) = h;          \
    dB0 += SQ8(va, vb);                                  \
    va = rg[S][6]; vb = rg[S][7];                        \
    CVT8(h, va, vb)                                      \
    *(bf16x8*)(&Bs[SB][(r1 * 4 + sl) * 8]) = h;          \
    dB1 += SQ8(va, vb); }

    // prologue: fill 3 slots (24 loads), write stage 0 into buffer 0
    ISSUE(0, 0);
    ISSUE(1, 1);
    ISSUE(2, 2);
    asm volatile("s_waitcnt vmcnt(16)" ::: "memory");   // stage 0 arrived
    CVW(0, 0);

    #pragma unroll
    for (int e = 0; e < 16; ++e) {
        // drain own ds_writes, then rendezvous: buffer e&1 fully staged
        asm volatile("s_waitcnt lgkmcnt(0)" ::: "memory");
        __builtin_amdgcn_s_barrier();
        __builtin_amdgcn_sched_barrier(0);

        if (e + 3 < 16) ISSUE(e % 3, e + 3);            // depth-2 issue

        const int rb = e & 1;
        bf16x8 af[4], bfr[4];
        #pragma unroll
        for (int mi = 0; mi < 4; ++mi) {
            const int row = wm * 64 + mi * 16 + l15;
            af[mi] = *(const bf16x8*)(&As[rb][(row * 4 + (quad ^ ((row >> 1) & 3))) * 8]);
        }
        #pragma unroll
        for (int nj = 0; nj < 4; ++nj) {
            const int row = wn * 64 + nj * 16 + l15;
            bfr[nj] = *(const bf16x8*)(&Bs[rb][(row * 4 + (quad ^ ((row >> 1) & 3))) * 8]);
        }
        __builtin_amdgcn_s_setprio(1);
        #pragma unroll
        for (int mi = 0; mi < 4; ++mi)
            #pragma unroll
            for (int nj = 0; nj < 4; ++nj)
                acc[mi][nj] = __builtin_amdgcn_mfma_f32_16x16x32_bf16(
                    af[mi], bfr[nj], acc[mi][nj], 0, 0, 0);
        __builtin_amdgcn_s_setprio(0);

        if (e + 1 < 16) {
            // wait for stage e+1's 8 loads (outstanding after: e+2, e+3 stages)
            if (e + 3 < 16)      asm volatile("s_waitcnt vmcnt(16)" ::: "memory");
            else if (e + 2 < 16) asm volatile("s_waitcnt vmcnt(8)"  ::: "memory");
            else                 asm volatile("s_waitcnt vmcnt(0)"  ::: "memory");
            CVW((e + 1) % 3, (e + 1) & 1);
        }
    }

    // ---------------- diag reduce (replaces prep's diag) ----------------
    // 4 threads (sl=0..3) hold disjoint-octet partials of each row.
    dA0 += __shfl_xor(dA0, 1); dA0 += __shfl_xor(dA0, 2);
    dA1 += __shfl_xor(dA1, 1); dA1 += __shfl_xor(dA1, 2);
    dB0 += __shfl_xor(dB0, 1); dB0 += __shfl_xor(dB0, 2);
    dB1 += __shfl_xor(dB1, 1); dB1 += __shfl_xor(dB1, 2);
    if (sl == 0) {
        const float inv2M = 1.0f / (2.0f * M_);
        dshA[r0] = dA0 * inv2M; dshA[r1] = dA1 * inv2M;
        dshB[r0] = dB0 * inv2M; dshB[r1] = dB1 * inv2M;
    }
    __syncthreads();

    // ---------------- epilogue (math identical to R9/R10) ----------------
    const int gi0 = ti * 128 + wm * 64;
    const int gj0 = tj * 128 + wn * 64;
    float di[4][4], dj[4];
    #pragma unroll
    for (int mi = 0; mi < 4; ++mi)
        #pragma unroll
        for (int r = 0; r < 4; ++r)
            di[mi][r] = dshA[wm * 64 + mi * 16 + quad * 4 + r];
    #pragma unroll
    for (int nj = 0; nj < 4; ++nj)
        dj[nj] = dshB[wn * 64 + nj * 16 + l15];

    float* outB = out + (size_t)b * OUTROW;
    __bf16* pB = pbuf + (size_t)b * OUTROW;
    float rs[4][4] = {};
    float cs[4] = {};
    float wt = 0.f;
    const float invK = 1.0f / 512.0f;  // dcov = di + dj - dot/512

    #pragma unroll
    for (int mi = 0; mi < 4; ++mi) {
        #pragma unroll
        for (int nj = 0; nj < 4; ++nj) {
            const f32x4 a = acc[mi][nj];
            const int j = gj0 + nj * 16 + l15;
            #pragma unroll
            for (int r = 0; r < 4; ++r) {
                const int i = gi0 + mi * 16 + quad * 4 + r;
                float d = di[mi][r] + dj[nj] - a[r] * invK;
                if (i == j) d = 0.0f;   // exact: ref has dcov(i,i) == 0
                d = fmaxf(d, 0.0f);
                const float p = __builtin_exp2f(ALPHA_ * __builtin_log2f(d + EPS_));
                rs[mi][r] += p;
                cs[nj] += p;
                wt += p;
                if (!diagTile || j >= i) {
                    const size_t idx =
                        (size_t)i * D_ - ((size_t)i * (i + 1)) / 2 + j;
                    if (useP) pB[idx] = (__bf16)p;   // uniform branch
                    else      outB[idx] = p;
                }
            }
        }
    }

    // row-sum contributions: reduce across l15 lanes
    #pragma unroll
    for (int mi = 0; mi < 4; ++mi) {
        #pragma unroll
        for (int r = 0; r < 4; ++r) {
            float v = rs[mi][r];
            v += __shfl_xor(v, 1); v += __shfl_xor(v, 2);
            v += __shfl_xor(v, 4); v += __shfl_xor(v, 8);
            if (l15 == 0)
                unsafeAtomicAdd(&rowsum[b * D_ + gi0 + mi * 16 + quad * 4 + r], v);
        }
    }
    // col-sum contributions map to rowsum[j] by symmetry (off-diag tiles only)
    if (!diagTile) {
        #pragma unroll
        for (int nj = 0; nj < 4; ++nj) {
            float v = cs[nj];
            v += __shfl_xor(v, 16); v += __shfl_xor(v, 32);
            if (quad == 0)
                unsafeAtomicAdd(&rowsum[b * D_ + gj0 + nj * 16 + l15], v);
        }
    }
    // batch total (off-diag tiles counted twice: tile + mirror)
    float v = wt;
    #pragma unroll
    for (int off = 32; off; off >>= 1) v += __shfl_down(v, off);
    if (l == 0) unsafeAtomicAdd(&totals[b], diagTile ? v : 2.0f * v);
}

// ---------------------------------------------------------------------------
// Kernel C: double-centering (R9-verbatim). Row-paired, rowsum pre-scaled in
// LDS. useP: read bf16 p, write fp32 out once. Fallback: in-place fp32 RMW.
// jA clamped to D (R7 bugfix): head/body/tail disjoint, in-bounds for all i.
// ---------------------------------------------------------------------------
__global__ __launch_bounds__(256) void center_kernel(
    float* __restrict__ out, const __bf16* __restrict__ pbuf,
    const float* __restrict__ rowsum, const float* __restrict__ totals,
    int useP)
{
    __shared__ float rs[D_];
    const int b = blockIdx.y;
    const int tid = threadIdx.x;

    // stage rowsum/D into LDS (coalesced float4)
    {
        const float4* src = (const float4*)(rowsum + b * D_);
        float4 v = src[tid];
        rs[tid * 4 + 0] = v.x * (1.0f / D_);
        rs[tid * 4 + 1] = v.y * (1.0f / D_);
        rs[tid * 4 + 2] = v.z * (1.0f / D_);
        rs[tid * 4 + 3] = v.w * (1.0f / D_);
    }
    __syncthreads();

    const float tm = totals[b] * (1.0f / ((float)D_ * (float)D_));
    float* outB = out + (size_t)b * OUTROW;
    const __bf16* pBb = pbuf + (size_t)b * OUTROW;

    #pragma unroll
    for (int h = 0; h < 2; ++h) {
        const int i = h ? (D_ - 1 - (int)blockIdx.x) : (int)blockIdx.x;
        const float rmi = rs[i];
        const size_t base = (size_t)i * D_ - ((size_t)i * (i + 1)) / 2;
        float* row = outB + base;
        const __bf16* prow = pBb + base;

        const int mis = (int)((base + i) & 3);
        int jA = i + ((4 - mis) & 3);
        if (jA > D_) jA = D_;                 // clamp (R7 bugfix)
        const int head = jA - i;              // 0..3 scalars, <= rowlen
        const int rem = D_ - jA;              // >= 0
        const int body4 = rem >> 2;           // 4-elem vector count
        const int tail = rem & 3;             // 0..3 scalars

        if (useP) {
            if (tid < head) {
                const int j = i + tid;
                row[j] = (float)prow[j] - rmi - rs[j] + tm;
            } else if (tid < head + tail) {
                const int j = D_ - tail + (tid - head);
                row[j] = (float)prow[j] - rmi - rs[j] + tm;
            }
            for (int v = tid; v < body4; v += 256) {
                const int j = jA + v * 4;
                bf16x4 pv = *(const bf16x4*)(prow + j);   // 8B aligned load
                float4 x;
                x.x = (float)pv[0] - rmi - rs[j + 0] + tm;
                x.y = (float)pv[1] - rmi - rs[j + 1] + tm;
                x.z = (float)pv[2] - rmi - rs[j + 2] + tm;
                x.w = (float)pv[3] - rmi - rs[j + 3] + tm;
                *(float4*)(row + j) = x;                  // 16B aligned store
            }
        } else {
            if (tid < head) {
                const int j = i + tid;
                row[j] = row[j] - rmi - rs[j] + tm;
            } else if (tid < head + tail) {
                const int j = D_ - tail + (tid - head);
                row[j] = row[j] - rmi - rs[j] + tm;
            }
            for (int v = tid; v < body4; v += 256) {
                const int j = jA + v * 4;
                float4 x = *(float4*)(row + j);
                x.x = x.x - rmi - rs[j + 0] + tm;
                x.y = x.y - rmi - rs[j + 1] + tm;
                x.z = x.z - rmi - rs[j + 2] + tm;
                x.w = x.w - rmi - rs[j + 3] + tm;
                *(float4*)(row + j) = x;
            }
        }
    }
}

// ---------------------------------------------------------------------------
extern "C" void kernel_launch(void* const* d_in, const int* in_sizes, int n_in,
                              void* d_out, int out_size, void* d_ws, size_t ws_size,
                              hipStream_t stream) {
    const float* feat = (const float*)d_in[0];
    float* out = (float*)d_out;

    char* ws = (char*)d_ws;
    // Layout (prep/featbf/diag deleted -- ws shrinks 67.4 -> 33.7 MB):
    __bf16* pbuf  = (__bf16*)ws;                          // 33,587,200 B
    float* rowsum = (float*)(ws + 33587200);              //    131,072 B
    float* totals = (float*)(ws + 33587200 + 131072);     //        128 B

    const size_t need = 33587200ull + 131072ull + 128ull;
    const int useP = (ws_size >= need) ? 1 : 0;
    if (!useP) {   // fallback: no pbuf; accumulators at ws base
        rowsum = (float*)ws;
        totals = (float*)(ws + 131072);
    }

    (void)hipMemsetAsync(rowsum, 0, 131072 + 128, stream);  // contiguous pair
    gram_kernel<<<dim3(36 * B_), dim3(256), 0, stream>>>(feat, out, pbuf,
                                                         rowsum, totals, useP);
    center_kernel<<<dim3(D_ / 2, B_), dim3(256), 0, stream>>>(out, pbuf, rowsum,
                                                              totals, useP);
}